// Round 1
// baseline (317.866 us; speedup 1.0000x reference)
//
#include <hip/hip_runtime.h>
#include <hip/hip_bf16.h>
#include <stdint.h>

// B=4, C=512, H=W=64 -> N=4096. Channel-first x [B,C,N].
#define C_DIM 512
#define N_DIM 4096
#define B_DIM 4

typedef __bf16 bf16x8 __attribute__((ext_vector_type(8)));
typedef float f32x4 __attribute__((ext_vector_type(4)));

static __device__ __forceinline__ unsigned short f2bf(float x) {
  // round-to-nearest-even f32 -> bf16 bits
  unsigned u = __float_as_uint(x);
  unsigned r = (u + 0x7fffu + ((u >> 16) & 1u)) >> 16;
  return (unsigned short)r;
}

__global__ __launch_bounds__(256) void cvt_weights(
    const float* __restrict__ w0, const float* __restrict__ w1,
    const float* __restrict__ w2, const float* __restrict__ w3,
    unsigned short* __restrict__ o0, unsigned short* __restrict__ o1,
    unsigned short* __restrict__ o2, unsigned short* __restrict__ o3) {
  int i = blockIdx.x * blockDim.x + threadIdx.x;
  if (i < C_DIM * C_DIM) {
    o0[i] = f2bf(w0[i]); o1[i] = f2bf(w1[i]);
    o2[i] = f2bf(w2[i]); o3[i] = f2bf(w3[i]);
  }
}

// x [B,C,N] f32 -> Xt [B,N,C] bf16
__global__ __launch_bounds__(256) void transpose_x(
    const float* __restrict__ x, unsigned short* __restrict__ Xt) {
  __shared__ float t[32][33];
  const int b = blockIdx.z;
  const float* xb = x + (size_t)b * C_DIM * N_DIM;
  unsigned short* xtb = Xt + (size_t)b * N_DIM * C_DIM;
  const int n0 = blockIdx.x * 32, c0 = blockIdx.y * 32;
  const int tx = threadIdx.x, ty = threadIdx.y;
  #pragma unroll
  for (int i = ty; i < 32; i += 8)
    t[i][tx] = xb[(size_t)(c0 + i) * N_DIM + n0 + tx];
  __syncthreads();
  #pragma unroll
  for (int i = ty; i < 32; i += 8)
    xtb[(size_t)(n0 + i) * C_DIM + c0 + tx] = f2bf(t[tx][i]);
}

// NT GEMM: C[i,j] = scale * sum_k A[i,k]*B[j,k]  (A:[M,K], B:[N,K], both row-major bf16)
// 128x128 tile, BK=32, 256 threads (4 waves, 2x2 of 64x64), mfma 16x16x32 bf16.
// BIAS: 0=none, 1=+bias[col], 2=+bias[row].  F32OUT: add resid and store f32, else store bf16.
template<int BIAS, bool F32OUT>
__global__ __launch_bounds__(256, 2) void gemm_nt(
    const unsigned short* __restrict__ A, long sA,
    const unsigned short* __restrict__ B, long sB,
    void* __restrict__ Cp, long sC,
    int M, int N, int K, int ldc,
    const float* __restrict__ bias,
    const float* __restrict__ resid, long sR,
    float scale) {
  const int z = blockIdx.z;
  A += (size_t)z * sA;
  B += (size_t)z * sB;
  const int tid = threadIdx.x;
  const int wid = tid >> 6, lane = tid & 63;
  __shared__ unsigned short As[128 * 32];
  __shared__ unsigned short Bs[128 * 32];
  const int wm = (wid >> 1) * 64, wn = (wid & 1) * 64;
  f32x4 acc[4][4] = {};
  const size_t rowA0 = (size_t)blockIdx.x * 128;
  const size_t rowB0 = (size_t)blockIdx.y * 128;
  // staging: each wave copies two 16-row chunks of each tile (16B/lane)
  const int sgrp = wid * 2;
  const int r0 = (sgrp * 64 + lane) >> 2;
  const int r1 = ((sgrp + 1) * 64 + lane) >> 2;
  const int cc = (lane & 3) * 8;
  const int lr = lane & 15;
  const int kh = (lane >> 4) * 8;

  for (int k0 = 0; k0 < K; k0 += 32) {
    __syncthreads();
    __builtin_amdgcn_global_load_lds(
        (const __attribute__((address_space(1))) void*)(A + (rowA0 + r0) * K + k0 + cc),
        (__attribute__((address_space(3))) void*)(As + sgrp * 512), 16, 0, 0);
    __builtin_amdgcn_global_load_lds(
        (const __attribute__((address_space(1))) void*)(A + (rowA0 + r1) * K + k0 + cc),
        (__attribute__((address_space(3))) void*)(As + (sgrp + 1) * 512), 16, 0, 0);
    __builtin_amdgcn_global_load_lds(
        (const __attribute__((address_space(1))) void*)(B + (rowB0 + r0) * K + k0 + cc),
        (__attribute__((address_space(3))) void*)(Bs + sgrp * 512), 16, 0, 0);
    __builtin_amdgcn_global_load_lds(
        (const __attribute__((address_space(1))) void*)(B + (rowB0 + r1) * K + k0 + cc),
        (__attribute__((address_space(3))) void*)(Bs + (sgrp + 1) * 512), 16, 0, 0);
    __syncthreads();
    bf16x8 af[4], bf[4];
    #pragma unroll
    for (int m = 0; m < 4; ++m)
      af[m] = *reinterpret_cast<const bf16x8*>(&As[(wm + m * 16 + lr) * 32 + kh]);
    #pragma unroll
    for (int n = 0; n < 4; ++n)
      bf[n] = *reinterpret_cast<const bf16x8*>(&Bs[(wn + n * 16 + lr) * 32 + kh]);
    #pragma unroll
    for (int m = 0; m < 4; ++m)
      #pragma unroll
      for (int n = 0; n < 4; ++n)
        acc[m][n] = __builtin_amdgcn_mfma_f32_16x16x32_bf16(af[m], bf[n], acc[m][n], 0, 0, 0);
  }

  const int rg = (lane >> 4) * 4;
  #pragma unroll
  for (int m = 0; m < 4; ++m) {
    #pragma unroll
    for (int n = 0; n < 4; ++n) {
      #pragma unroll
      for (int r = 0; r < 4; ++r) {
        int row = (int)rowA0 + wm + m * 16 + rg + r;
        int col = (int)rowB0 + wn + n * 16 + lr;
        float v = acc[m][n][r] * scale;
        if (BIAS == 1) v += bias[col];
        if (BIAS == 2) v += bias[row];
        size_t idx = (size_t)row * ldc + col;
        if (F32OUT) {
          float* Cf = (float*)Cp + (size_t)z * sC;
          Cf[idx] = v + resid[(size_t)z * sR + idx];
        } else {
          ((unsigned short*)Cp + (size_t)z * sC)[idx] = f2bf(v);
        }
      }
    }
  }
}

// in-place row softmax over rows of 4096 bf16; one block (256 thr) per row
__global__ __launch_bounds__(256) void softmax_rows(unsigned short* __restrict__ P) {
  const size_t row = blockIdx.x;
  unsigned short* pr = P + row * N_DIM;
  const int tid = threadIdx.x;
  const int lane = tid & 63, wid = tid >> 6;
  uint4 u0 = reinterpret_cast<const uint4*>(pr)[tid * 2];
  uint4 u1 = reinterpret_cast<const uint4*>(pr)[tid * 2 + 1];
  unsigned ua[8] = {u0.x, u0.y, u0.z, u0.w, u1.x, u1.y, u1.z, u1.w};
  float f[16];
  #pragma unroll
  for (int i = 0; i < 8; ++i) {
    f[2 * i]     = __uint_as_float(ua[i] << 16);
    f[2 * i + 1] = __uint_as_float(ua[i] & 0xffff0000u);
  }
  float m = f[0];
  #pragma unroll
  for (int i = 1; i < 16; ++i) m = fmaxf(m, f[i]);
  #pragma unroll
  for (int off = 32; off >= 1; off >>= 1) m = fmaxf(m, __shfl_xor(m, off));
  __shared__ float red[4], red2[4];
  if (lane == 0) red[wid] = m;
  __syncthreads();
  m = fmaxf(fmaxf(red[0], red[1]), fmaxf(red[2], red[3]));
  float s = 0.f;
  #pragma unroll
  for (int i = 0; i < 16; ++i) { f[i] = __expf(f[i] - m); s += f[i]; }
  #pragma unroll
  for (int off = 32; off >= 1; off >>= 1) s += __shfl_xor(s, off);
  if (lane == 0) red2[wid] = s;
  __syncthreads();
  s = red2[0] + red2[1] + red2[2] + red2[3];
  const float inv = 1.0f / s;
  unsigned ob[8];
  #pragma unroll
  for (int i = 0; i < 8; ++i) {
    unsigned lo = f2bf(f[2 * i] * inv);
    unsigned hi = f2bf(f[2 * i + 1] * inv);
    ob[i] = lo | (hi << 16);
  }
  uint4 o0 = {ob[0], ob[1], ob[2], ob[3]}, o1 = {ob[4], ob[5], ob[6], ob[7]};
  reinterpret_cast<uint4*>(pr)[tid * 2] = o0;
  reinterpret_cast<uint4*>(pr)[tid * 2 + 1] = o1;
}

extern "C" void kernel_launch(void* const* d_in, const int* in_sizes, int n_in,
                              void* d_out, int out_size, void* d_ws, size_t ws_size,
                              hipStream_t stream) {
  const float* x  = (const float*)d_in[0];
  const float* wq = (const float*)d_in[1];
  const float* bq = (const float*)d_in[2];
  const float* wk = (const float*)d_in[3];
  const float* bk = (const float*)d_in[4];
  const float* wv = (const float*)d_in[5];
  const float* bv = (const float*)d_in[6];
  const float* wp = (const float*)d_in[7];
  const float* bp = (const float*)d_in[8];
  float* out = (float*)d_out;
  char* ws = (char*)d_ws;
  const size_t MB = 1024 * 1024;
  unsigned short* Wq = (unsigned short*)(ws + 0);
  unsigned short* Wk = (unsigned short*)(ws + 512 * 1024);
  unsigned short* Wv = (unsigned short*)(ws + 1 * MB);
  unsigned short* Wp = (unsigned short*)(ws + MB + 512 * 1024);
  unsigned short* Xt = (unsigned short*)(ws + 2 * MB);    // [B,N,C] bf16, 16MB
  unsigned short* Qb = (unsigned short*)(ws + 18 * MB);   // [B,N,C]
  unsigned short* Kb = (unsigned short*)(ws + 34 * MB);   // [B,N,C]
  unsigned short* Vt = (unsigned short*)(ws + 50 * MB);   // [B,C,N]
  unsigned short* At = (unsigned short*)(ws + 66 * MB);   // [B,N,C]
  unsigned short* P  = (unsigned short*)(ws + 82 * MB);   // [N,N] x (1 or 4 batches)
  const long NCe = (long)N_DIM * C_DIM;
  const long NNe = (long)N_DIM * N_DIM;
  const float rs = 0.044194173824159216f;  // 1/sqrt(512)
  const bool big = ws_size >= 82 * MB + 4 * (size_t)N_DIM * N_DIM * 2;

  cvt_weights<<<dim3((C_DIM * C_DIM + 255) / 256), dim3(256), 0, stream>>>(
      wq, wk, wv, wp, Wq, Wk, Wv, Wp);
  transpose_x<<<dim3(N_DIM / 32, C_DIM / 32, B_DIM), dim3(32, 8), 0, stream>>>(x, Xt);
  // Q[n,o] = Xt . Wq^T + bq ; K likewise
  gemm_nt<1, false><<<dim3(32, 4, 4), 256, 0, stream>>>(
      Xt, NCe, Wq, 0, Qb, NCe, N_DIM, C_DIM, C_DIM, C_DIM, bq, nullptr, 0, 1.0f);
  gemm_nt<1, false><<<dim3(32, 4, 4), 256, 0, stream>>>(
      Xt, NCe, Wk, 0, Kb, NCe, N_DIM, C_DIM, C_DIM, C_DIM, bk, nullptr, 0, 1.0f);
  // Vt[o,n] = Wv . Xt^T + bv (row bias)
  gemm_nt<2, false><<<dim3(4, 32, 4), 256, 0, stream>>>(
      Wv, 0, Xt, NCe, Vt, NCe, C_DIM, N_DIM, C_DIM, N_DIM, bv, nullptr, 0, 1.0f);

  if (big) {
    gemm_nt<0, false><<<dim3(32, 32, 4), 256, 0, stream>>>(
        Qb, NCe, Kb, NCe, P, NNe, N_DIM, N_DIM, C_DIM, N_DIM, nullptr, nullptr, 0, rs);
    softmax_rows<<<dim3(B_DIM * N_DIM), 256, 0, stream>>>(P);
    gemm_nt<0, false><<<dim3(32, 4, 4), 256, 0, stream>>>(
        P, NNe, Vt, NCe, At, NCe, N_DIM, C_DIM, N_DIM, C_DIM, nullptr, nullptr, 0, 1.0f);
  } else {
    for (int b = 0; b < B_DIM; ++b) {
      gemm_nt<0, false><<<dim3(32, 32, 1), 256, 0, stream>>>(
          Qb + (size_t)b * NCe, 0, Kb + (size_t)b * NCe, 0, P, 0,
          N_DIM, N_DIM, C_DIM, N_DIM, nullptr, nullptr, 0, rs);
      softmax_rows<<<dim3(N_DIM), 256, 0, stream>>>(P);
      gemm_nt<0, false><<<dim3(32, 4, 1), 256, 0, stream>>>(
          P, 0, Vt + (size_t)b * NCe, 0, At + (size_t)b * NCe, 0,
          N_DIM, C_DIM, N_DIM, C_DIM, nullptr, nullptr, 0, 1.0f);
    }
  }
  // out[o,n] = Wp . At^T + bp[o] + x
  gemm_nt<2, true><<<dim3(4, 32, 4), 256, 0, stream>>>(
      Wp, 0, At, NCe, out, NCe, C_DIM, N_DIM, C_DIM, N_DIM, bp, x, NCe, 1.0f);
}